// Round 11
// baseline (77.092 us; speedup 1.0000x reference)
//
#include <hip/hip_runtime.h>

#define N_ATOMS 8388608
#define N_MOLS  262144
#define N_PAIRS (N_ATOMS / 2)        // 4194304
#define HALF    (N_PAIRS / 2)        // 2097152 threads; chunk B at +HALF

// DPP cross-lane helpers (VALU-only). Masked/invalid lanes keep `old`:
// key old=-1 (never matches), value old=0.
template<int CTRL, int RM>
__device__ __forceinline__ int dpp_key(int v) {
    return __builtin_amdgcn_update_dpp(-1, v, CTRL, RM, 0xf, false);
}
template<int CTRL, int RM>
__device__ __forceinline__ float dpp_val(float v) {
    return __int_as_float(
        __builtin_amdgcn_update_dpp(0, __float_as_int(v), CTRL, RM, 0xf, false));
}

// Pass 1 (template A/B): 2 pair-chunks/thread, coalesced loads.
// Boundary pairs: atom0 packet passed DOWN one lane and absorbed into the
// predecessor's pre-scan partial (predecessor is then the segment tail, so
// the absorbed value flushes with its molecule). Complementary self-flush
// (prevTail != atom0-mol, incl. lane 0) fires in ~3% of waves, execz-skipped.
// Then 6-step DPP segmented inclusive scan; segment tails flush.
// REAL=true: unsafeAtomicAdd to accumulators. REAL=false (probe): identical
// work, flushes accumulate in registers -> one coalesced store to scratch.
template<bool REAL>
__global__ __launch_bounds__(256) void ce_pass1_t(
    const float4* __restrict__ h4, const float2* __restrict__ q2,
    const int2* __restrict__ mol2,
    float* __restrict__ sum_qe, float* __restrict__ sum_si,
    float2* __restrict__ scratch)
{
    const int g = blockIdx.x * blockDim.x + threadIdx.x;   // 0 .. HALF-1
    const int lane = threadIdx.x & 63;
    float accq = 0.f, accs = 0.f;                          // probe-only

    float4 hA = h4[g];       float4 hB = h4[g + HALF];
    float2 qA = q2[g];       float2 qB = q2[g + HALF];
    int2   mA = mol2[g];     int2   mB = mol2[g + HALF];

    // ---- chunk A pre-combine + neighbor handoff ----
    float siA0 = 1.0f / hA.y, siA1 = 1.0f / hA.w;
    float qeA0 = qA.x + hA.x * siA0, qeA1 = qA.y + hA.z * siA1;
    bool  bA   = (mA.x != mA.y);
    int   keyA = mA.y;
    float pqA  = bA ? qeA1 : (qeA0 + qeA1);
    float psA  = bA ? siA1 : (siA0 + siA1);
    int   prevTailA = __shfl_up(keyA, 1, 64);   // lane0: own key (=> self-flush path)
    int   rbA   = __shfl_down((int)bA, 1, 64);
    int   rkeyA = __shfl_down(mA.x, 1, 64);
    float rqA   = __shfl_down(qeA0, 1, 64);
    float rsA   = __shfl_down(siA0, 1, 64);
    if (rbA && rkeyA == keyA) { pqA += rqA; psA += rsA; }  // absorb next lane's atom0
    if (bA && prevTailA != mA.x) {                         // rare self-flush
        if (REAL) {
            unsafeAtomicAdd(&sum_qe[mA.x], qeA0);
            unsafeAtomicAdd(&sum_si[mA.x], siA0);
        } else { accq += qeA0; accs += siA0; }
    }

    // ---- chunk B pre-combine + neighbor handoff ----
    float siB0 = 1.0f / hB.y, siB1 = 1.0f / hB.w;
    float qeB0 = qB.x + hB.x * siB0, qeB1 = qB.y + hB.z * siB1;
    bool  bB   = (mB.x != mB.y);
    int   keyB = mB.y;
    float pqB  = bB ? qeB1 : (qeB0 + qeB1);
    float psB  = bB ? siB1 : (siB0 + siB1);
    int   prevTailB = __shfl_up(keyB, 1, 64);
    int   rbB   = __shfl_down((int)bB, 1, 64);
    int   rkeyB = __shfl_down(mB.x, 1, 64);
    float rqB   = __shfl_down(qeB0, 1, 64);
    float rsB   = __shfl_down(siB0, 1, 64);
    if (rbB && rkeyB == keyB) { pqB += rqB; psB += rsB; }
    if (bB && prevTailB != mB.x) {
        if (REAL) {
            unsafeAtomicAdd(&sum_qe[mB.x], qeB0);
            unsafeAtomicAdd(&sum_si[mB.x], siB0);
        } else { accq += qeB0; accs += siB0; }
    }

    // ---- 6-step DPP segmented inclusive scan, A/B interleaved ----
#define SCAN_STEP(CTRL, RM)                                               \
    {                                                                     \
        int   kA  = dpp_key<CTRL, RM>(keyA);                              \
        int   kB  = dpp_key<CTRL, RM>(keyB);                              \
        float vqA = dpp_val<CTRL, RM>(pqA);                               \
        float vsA = dpp_val<CTRL, RM>(psA);                               \
        float vqB = dpp_val<CTRL, RM>(pqB);                               \
        float vsB = dpp_val<CTRL, RM>(psB);                               \
        if (kA == keyA) { pqA += vqA; psA += vsA; }                       \
        if (kB == keyB) { pqB += vqB; psB += vsB; }                       \
    }
    SCAN_STEP(0x111, 0xf)   // row_shr:1
    SCAN_STEP(0x112, 0xf)   // row_shr:2
    SCAN_STEP(0x114, 0xf)   // row_shr:4
    SCAN_STEP(0x118, 0xf)   // row_shr:8
    SCAN_STEP(0x142, 0xa)   // row_bcast:15 -> rows 1,3
    SCAN_STEP(0x143, 0xc)   // row_bcast:31 -> rows 2,3
#undef SCAN_STEP

    // ---- segment-tail flush ----
    int nkA = __shfl_down(keyA, 1, 64);
    int nkB = __shfl_down(keyB, 1, 64);
    if (lane == 63 || nkA != keyA) {
        if (REAL) {
            unsafeAtomicAdd(&sum_qe[keyA], pqA);
            unsafeAtomicAdd(&sum_si[keyA], psA);
        } else { accq += pqA; accs += psA; }
    }
    if (lane == 63 || nkB != keyB) {
        if (REAL) {
            unsafeAtomicAdd(&sum_qe[keyB], pqB);
            unsafeAtomicAdd(&sum_si[keyB], psB);
        } else { accq += pqB; accs += psB; }
    }
    if (!REAL) scratch[g] = make_float2(accq, accs);
}

// Pass 2: t = sum_qe / sum_si
__global__ __launch_bounds__(256) void ce_pass2(
    const float* __restrict__ sum_qe, const float* __restrict__ sum_si,
    float* __restrict__ t)
{
    int m = blockIdx.x * blockDim.x + threadIdx.x;
    t[m] = sum_qe[m] / sum_si[m];
}

// Pass 3: 4 atoms/thread, coalesced mol/out; t gather sorted + L2-resident.
__global__ __launch_bounds__(256) void ce_pass3(
    const float4* __restrict__ h4, const int4* __restrict__ mol4,
    const float* __restrict__ tmol, float4* __restrict__ out4)
{
    int g = blockIdx.x * 256 + threadIdx.x;   // over N_ATOMS/4
    int4   m4 = mol4[g];
    float4 hA = h4[g * 2];
    float4 hB = h4[g * 2 + 1];
    float4 o;
    o.x = (tmol[m4.x] - hA.x) / hA.y;
    o.y = (tmol[m4.y] - hA.z) / hA.w;
    o.z = (tmol[m4.z] - hB.x) / hB.y;
    o.w = (tmol[m4.w] - hB.z) / hB.w;
    out4[g] = o;
}

extern "C" void kernel_launch(void* const* d_in, const int* in_sizes, int n_in,
                              void* d_out, int out_size, void* d_ws, size_t ws_size,
                              hipStream_t stream) {
    const float4* h4   = (const float4*)d_in[0];
    const float2* q2   = (const float2*)d_in[1];
    const int2*   mol2 = (const int2*)d_in[2];
    const int4*   mol4 = (const int4*)d_in[2];
    float4* out4 = (float4*)d_out;

    float*  sum_qe  = (float*)d_ws;
    float*  sum_si  = sum_qe + N_MOLS;
    float*  tmol    = sum_si + N_MOLS;
    float2* scratch = (float2*)((char*)d_ws + (16u << 20));  // probe-only sink

    hipMemsetAsync(d_ws, 0, (size_t)2 * N_MOLS * sizeof(float), stream);

    ce_pass1_t<true><<<HALF / 256, 256, 0, stream>>>(h4, q2, mol2,
                                                     sum_qe, sum_si, scratch);
    ce_pass2<<<N_MOLS / 256, 256, 0, stream>>>(sum_qe, sum_si, tmol);
    ce_pass3<<<N_ATOMS / 4 / 256, 256, 0, stream>>>(h4, mol4, tmol, out4);

    // diagnostic probe: identical work, no atomics (separate rocprof row;
    // writes only scratch — cannot affect correctness)
    ce_pass1_t<false><<<HALF / 256, 256, 0, stream>>>(h4, q2, mol2,
                                                      sum_qe, sum_si, scratch);
}

// Round 13
// 62.951 us; speedup vs baseline: 1.2246x; 1.2246x over previous
//
#include <hip/hip_runtime.h>

#define N_ATOMS 8388608
#define N_MOLS  262144
#define N_PAIRS (N_ATOMS / 2)        // 4194304 pairs
#define HALF    (N_PAIRS / 2)        // 2097152 threads in pass1
#define NCHUNKS (N_PAIRS / 64)       // 65536 wave-chunks of 128 atoms
#define NENTRY  (3 * NCHUNKS)        // boundary entries (3 per chunk)

// DPP cross-lane helpers (VALU-only). Masked/invalid lanes keep `old`:
// key old=-1 (never matches), value old=0.
template<int CTRL, int RM>
__device__ __forceinline__ int dpp_key(int v) {
    return __builtin_amdgcn_update_dpp(-1, v, CTRL, RM, 0xf, false);
}
template<int CTRL, int RM>
__device__ __forceinline__ float dpp_val(float v) {
    return __int_as_float(
        __builtin_amdgcn_update_dpp(0, __float_as_int(v), CTRL, RM, 0xf, false));
}

// One 128-atom wave-chunk: pair pre-combine + neighbor handoff + DPP
// segmented scan. NO atomics: interior molecules (provably exclusive to this
// chunk) are plain-stored; the <=3 boundary partials go to the entry list.
// Every entry slot is written every call (key=-1 marks empty) -> no init.
__device__ __forceinline__ void process_chunk(
    float4 hv, float2 qv, int2 mv, int lane, int chunkId,
    float* __restrict__ sum_qe, float* __restrict__ sum_si,
    int* __restrict__ bkey, float2* __restrict__ bval)
{
    float si0 = 1.0f / hv.y, si1 = 1.0f / hv.w;
    float qe0 = qv.x + hv.x * si0, qe1 = qv.y + hv.z * si1;
    bool  b   = (mv.x != mv.y);          // pair straddles a boundary
    int   key = mv.y;                    // post-combine key
    float pq  = b ? qe1 : (qe0 + qe1);
    float ps  = b ? si1 : (si0 + si1);

    // absorb next lane's atom0 if it belongs to my molecule (lane63: chunk-
    // external, handled as next chunk's entry)
    int   rb = __shfl_down((int)b, 1, 64);
    int   rk = __shfl_down(mv.x, 1, 64);
    float rq = __shfl_down(qe0, 1, 64);
    float rs = __shfl_down(si0, 1, 64);
    if (lane < 63 && rb && rk == key) { pq += rq; ps += rs; }

    int prevKey = __shfl_up(key, 1, 64);  // valid for lane>0
    // my own atom0 when the pair straddles:
    if (b) {
        if (lane == 0) {                  // may extend into previous chunk
            bkey[3 * chunkId] = mv.x;
            bval[3 * chunkId] = make_float2(qe0, si0);
        } else if (prevKey != mv.x) {     // single-atom molecule: exclusive
            sum_qe[mv.x] = qe0;
            sum_si[mv.x] = si0;
        }                                 // else: absorbed by predecessor
    } else if (lane == 0) {
        bkey[3 * chunkId] = -1;
    }

    // 6-step DPP segmented inclusive scan over (key, pq, ps)
#define SCAN_STEP(CTRL, RM)                                 \
    {                                                       \
        int   k  = dpp_key<CTRL, RM>(key);                  \
        float vq = dpp_val<CTRL, RM>(pq);                   \
        float vs = dpp_val<CTRL, RM>(ps);                   \
        if (k == key) { pq += vq; ps += vs; }               \
    }
    SCAN_STEP(0x111, 0xf)   // row_shr:1
    SCAN_STEP(0x112, 0xf)   // row_shr:2
    SCAN_STEP(0x114, 0xf)   // row_shr:4
    SCAN_STEP(0x118, 0xf)   // row_shr:8
    SCAN_STEP(0x142, 0xa)   // row_bcast:15 -> rows 1,3
    SCAN_STEP(0x143, 0xc)   // row_bcast:31 -> rows 2,3
#undef SCAN_STEP

    int fk = __shfl(key, 0, 64);
    int lk = __shfl(key, 63, 64);
    int nk = __shfl_down(key, 1, 64);
    bool tail = (lane == 63) || (nk != key);

    if (lane == 63) {
        // last-molecule partial: may extend into next chunk
        bkey[3 * chunkId + 2] = key;
        bval[3 * chunkId + 2] = make_float2(pq, ps);
        if (fk == lk) bkey[3 * chunkId + 1] = -1;   // no separate fk segment
    } else if (tail) {
        if (key == fk) {
            // first-molecule partial: may extend into previous chunk
            bkey[3 * chunkId + 1] = key;
            bval[3 * chunkId + 1] = make_float2(pq, ps);
        } else {
            // strictly interior molecule: this chunk owns it exclusively
            sum_qe[key] = pq;
            sum_si[key] = ps;
        }
    }
}

// Pass 1: 2 wave-chunks per wave (A at g, B at g+HALF), coalesced loads
// (h: float4/lane, q: float2, mol: int2). Zero atomics.
__global__ __launch_bounds__(256) void ce_pass1(
    const float4* __restrict__ h4, const float2* __restrict__ q2,
    const int2* __restrict__ mol2,
    float* __restrict__ sum_qe, float* __restrict__ sum_si,
    int* __restrict__ bkey, float2* __restrict__ bval)
{
    const int g = blockIdx.x * blockDim.x + threadIdx.x;   // 0 .. HALF-1
    const int lane = threadIdx.x & 63;
    const int chunkA = g >> 6;
    const int chunkB = chunkA + (NCHUNKS / 2);

    float4 hA = h4[g];       float4 hB = h4[g + HALF];
    float2 qA = q2[g];       float2 qB = q2[g + HALF];
    int2   mA = mol2[g];     int2   mB = mol2[g + HALF];

    process_chunk(hA, qA, mA, lane, chunkA, sum_qe, sum_si, bkey, bval);
    process_chunk(hB, qB, mB, lane, chunkB, sum_qe, sum_si, bkey, bval);
}

// Flush: atomic-merge the boundary partials (the ONLY atomics, in a tiny
// kernel with no streaming traffic to interfere with).
__global__ __launch_bounds__(256) void ce_flush(
    const int* __restrict__ bkey, const float2* __restrict__ bval,
    float* __restrict__ sum_qe, float* __restrict__ sum_si)
{
    int i = blockIdx.x * blockDim.x + threadIdx.x;   // 0 .. NENTRY-1
    int k = bkey[i];
    if (k >= 0) {
        float2 v = bval[i];
        unsafeAtomicAdd(&sum_qe[k], v.x);
        unsafeAtomicAdd(&sum_si[k], v.y);
    }
}

// Pass 2: t = sum_qe / sum_si
__global__ __launch_bounds__(256) void ce_pass2(
    const float* __restrict__ sum_qe, const float* __restrict__ sum_si,
    float* __restrict__ t)
{
    int m = blockIdx.x * blockDim.x + threadIdx.x;
    t[m] = sum_qe[m] / sum_si[m];
}

// Pass 3: 4 atoms/thread, coalesced mol/out; t gather sorted + L2-resident.
__global__ __launch_bounds__(256) void ce_pass3(
    const float4* __restrict__ h4, const int4* __restrict__ mol4,
    const float* __restrict__ tmol, float4* __restrict__ out4)
{
    int g = blockIdx.x * 256 + threadIdx.x;   // over N_ATOMS/4
    int4   m4 = mol4[g];
    float4 hA = h4[g * 2];
    float4 hB = h4[g * 2 + 1];
    float4 o;
    o.x = (tmol[m4.x] - hA.x) / hA.y;
    o.y = (tmol[m4.y] - hA.z) / hA.w;
    o.z = (tmol[m4.z] - hB.x) / hB.y;
    o.w = (tmol[m4.w] - hB.z) / hB.w;
    out4[g] = o;
}

extern "C" void kernel_launch(void* const* d_in, const int* in_sizes, int n_in,
                              void* d_out, int out_size, void* d_ws, size_t ws_size,
                              hipStream_t stream) {
    const float4* h4   = (const float4*)d_in[0];
    const float2* q2   = (const float2*)d_in[1];
    const int2*   mol2 = (const int2*)d_in[2];
    const int4*   mol4 = (const int4*)d_in[2];
    float4* out4 = (float4*)d_out;

    float*  sum_qe = (float*)d_ws;                       // 1 MB
    float*  sum_si = sum_qe + N_MOLS;                    // 1 MB
    float*  tmol   = sum_si + N_MOLS;                    // 1 MB
    int*    bkey   = (int*)(tmol + N_MOLS);              // 768 KB
    float2* bval   = (float2*)(bkey + NENTRY);           // 1.5 MB (8B-aligned)

    hipMemsetAsync(d_ws, 0, (size_t)2 * N_MOLS * sizeof(float), stream);

    ce_pass1<<<HALF / 256, 256, 0, stream>>>(h4, q2, mol2, sum_qe, sum_si,
                                             bkey, bval);
    ce_flush<<<NENTRY / 256, 256, 0, stream>>>(bkey, bval, sum_qe, sum_si);
    ce_pass2<<<N_MOLS / 256, 256, 0, stream>>>(sum_qe, sum_si, tmol);
    ce_pass3<<<N_ATOMS / 4 / 256, 256, 0, stream>>>(h4, mol4, tmol, out4);
}